// Round 10
// baseline (228.162 us; speedup 1.0000x reference)
//
#include <hip/hip_runtime.h>
#include <math.h>

#define B_DIM 4
#define F_DIM 512
#define T_DIM 2048
#define H_DIM 4
#define HF    128

typedef __attribute__((ext_vector_type(8))) short short8;
typedef __attribute__((ext_vector_type(4))) float floatx4;

// round-half-up bf16 (2 inst)
__device__ __forceinline__ unsigned short f2bf(float f) {
    return (unsigned short)((__float_as_uint(f) + 0x8000u) >> 16);
}

// two floats -> packed bf16 pair: 2 adds + 1 v_perm_b32
__device__ __forceinline__ unsigned pkbf2(float a, float b) {
    const unsigned ua = __float_as_uint(a) + 0x8000u;
    const unsigned ub = __float_as_uint(b) + 0x8000u;
    return __builtin_amdgcn_perm(ub, ua, 0x07060302u);  // [ua.hi16 | ub.hi16]
}

__device__ __forceinline__ short8 pack8(const float* v) {
    union { unsigned u[4]; short8 s; } r;
    #pragma unroll
    for (int j = 0; j < 4; ++j) r.u[j] = pkbf2(v[2*j], v[2*j+1]);
    return r.s;
}

// ---------------- Kernel 0: prep ----------------
__global__ __launch_bounds__(256)
void prep_kernel(const float* __restrict__ x,
                 const float* __restrict__ Wq, const float* __restrict__ Wk,
                 const float* __restrict__ Wv,
                 unsigned short* __restrict__ xt,
                 unsigned short* __restrict__ Wqb, unsigned short* __restrict__ Wkb,
                 unsigned short* __restrict__ Wvb)
{
    const int tid = threadIdx.x;
    if (blockIdx.z < B_DIM) {
        const int b  = blockIdx.z;
        const int t0 = blockIdx.x * 64;
        const int f0 = blockIdx.y * 64;
        __shared__ float Ls[64][67];
        const float* __restrict__ xb = x + (size_t)b * F_DIM * T_DIM;
        #pragma unroll
        for (int it = 0; it < 4; ++it) {
            const int fr = (tid >> 4) + 16 * it;
            const int tc = (tid & 15) << 2;
            const float4 v = *(const float4*)(xb + (size_t)(f0 + fr) * T_DIM + t0 + tc);
            Ls[fr][tc+0] = v.x; Ls[fr][tc+1] = v.y; Ls[fr][tc+2] = v.z; Ls[fr][tc+3] = v.w;
        }
        __syncthreads();
        const int f8 = tid & 7;
        const int tb = tid >> 3;
        #pragma unroll
        for (int it2 = 0; it2 < 2; ++it2) {
            const int t = tb + 32 * it2;
            float v[8];
            #pragma unroll
            for (int j = 0; j < 8; ++j) v[j] = Ls[8*f8 + j][t];
            *(short8*)(xt + ((size_t)b * T_DIM + t0 + t) * F_DIM + f0 + 8*f8) = pack8(v);
        }
    } else {
        const int blockId = blockIdx.y * 32 + blockIdx.x;
        const int g0 = blockId * 256 + tid;
        const int perW = F_DIM * F_DIM / 8;
        for (int chunk = g0; chunk < 3 * perW; chunk += 65536) {
            const int wsel = chunk / perW;
            const int rem  = chunk - wsel * perW;
            const float* __restrict__ Ws = (wsel == 0) ? Wq : (wsel == 1) ? Wk : Wv;
            unsigned short* __restrict__ Wd = (wsel == 0) ? Wqb : (wsel == 1) ? Wkb : Wvb;
            float v[8];
            *(float4*)&v[0] = *(const float4*)(Ws + (size_t)rem * 8);
            *(float4*)&v[4] = *(const float4*)(Ws + (size_t)rem * 8 + 4);
            *(short8*)(Wd + (size_t)rem * 8) = pack8(v);
        }
    }
}

// ---------------- Kernel 1: merged QKV projection, BK=128 ----------------
#define ASTR 136

__global__ __launch_bounds__(256, 3)
void proj_kernel(const unsigned short* __restrict__ xt,
                 const unsigned short* __restrict__ Wqb,
                 const unsigned short* __restrict__ Wkb,
                 const unsigned short* __restrict__ Wvb,
                 const float* __restrict__ bq, const float* __restrict__ bk,
                 const float* __restrict__ bv,
                 unsigned short* __restrict__ Qb, unsigned short* __restrict__ Kb,
                 unsigned short* __restrict__ Vtb)
{
    __shared__ unsigned short As[128][ASTR];
    __shared__ unsigned short Bs[64][ASTR];

    const int tid  = threadIdx.x;
    const int w    = tid >> 6;
    const int lane = tid & 63;
    const int ln15 = lane & 15;
    const int quad = lane >> 4;

    const bool is_v = (blockIdx.z >= 8);
    int t0, fo0, b;
    const unsigned short *Asrc, *Bsrc;
    if (!is_v) {
        t0  = blockIdx.x * 128;
        fo0 = blockIdx.y * 64;
        b   = blockIdx.z >> 1;
        Asrc = xt + (size_t)b * T_DIM * F_DIM + (size_t)t0 * F_DIM;
        Bsrc = ((blockIdx.z & 1) ? Wkb : Wqb) + (size_t)fo0 * F_DIM;
    } else {
        const int idx = blockIdx.y * 16 + blockIdx.x;   // 0..127
        fo0 = (idx >> 5) * 128;
        t0  = (idx & 31) * 64;
        b   = blockIdx.z - 8;
        Asrc = Wvb + (size_t)fo0 * F_DIM;
        Bsrc = xt + (size_t)b * T_DIM * F_DIM + (size_t)t0 * F_DIM;
    }

    floatx4 acc[2][4];
    #pragma unroll
    for (int mi = 0; mi < 2; ++mi)
        #pragma unroll
        for (int nt = 0; nt < 4; ++nt) acc[mi][nt] = (floatx4){0.f,0.f,0.f,0.f};

    for (int f0 = 0; f0 < F_DIM; f0 += 128) {
        __syncthreads();
        #pragma unroll
        for (int it = 0; it < 8; ++it) {
            const int idx = tid + it * 256;
            const int r = idx >> 4, c = (idx & 15) * 8;
            *(short8*)&As[r][c] = *(const short8*)(Asrc + (size_t)r * F_DIM + f0 + c);
        }
        #pragma unroll
        for (int it = 0; it < 4; ++it) {
            const int idx = tid + it * 256;
            const int r = idx >> 4, c = (idx & 15) * 8;
            *(short8*)&Bs[r][c] = *(const short8*)(Bsrc + (size_t)r * F_DIM + f0 + c);
        }
        __syncthreads();
        #pragma unroll
        for (int ks = 0; ks < 4; ++ks) {
            short8 a[2], bb[4];
            a[0] = *(const short8*)&As[w*32      + ln15][ks*32 + quad*8];
            a[1] = *(const short8*)&As[w*32 + 16 + ln15][ks*32 + quad*8];
            #pragma unroll
            for (int nt = 0; nt < 4; ++nt)
                bb[nt] = *(const short8*)&Bs[16*nt + ln15][ks*32 + quad*8];
            #pragma unroll
            for (int mi = 0; mi < 2; ++mi)
                #pragma unroll
                for (int nt = 0; nt < 4; ++nt)
                    acc[mi][nt] = __builtin_amdgcn_mfma_f32_16x16x32_bf16(
                        a[mi], bb[nt], acc[mi][nt], 0, 0, 0);
        }
    }

    if (!is_v) {
        const int which = blockIdx.z & 1;
        const float* bias = which ? bk : bq;
        unsigned short* __restrict__ Out =
            (which ? Kb : Qb) + (size_t)b * T_DIM * F_DIM;
        // Q carries 1/sqrt(F/2) * log2(e) so attn uses exp2 (native v_exp_f32)
        const float oscale = which ? 1.0f : 0.0625f * 1.4426950408889634f;
        float bn[4];
        #pragma unroll
        for (int nt = 0; nt < 4; ++nt) bn[nt] = bias[fo0 + 16*nt + ln15];
        const float pw[2] = {
            __uint_as_float((unsigned)(123 - ln15) << 23),   // 2^-(ln15+4)
            __uint_as_float((unsigned)(107 - ln15) << 23)    // 2^-(ln15+20)
        };
        #pragma unroll
        for (int mi = 0; mi < 2; ++mi) {
            #pragma unroll
            for (int r = 0; r < 4; ++r) {
                const int t = t0 + w*32 + 16*mi + quad*4 + r;
                unsigned short* rowp = Out + (size_t)t * F_DIM + fo0;
                #pragma unroll
                for (int pr = 0; pr < 2; ++pr) {
                    const int wi = 16*pr + ln15;
                    const float re = acc[mi][pr  ][r] + bn[pr];
                    const float im = acc[mi][pr+2][r] + bn[pr+2];
                    const float u = (float)t * pw[pr];
                    float sn, cs;
                    __sincosf(u, &sn, &cs);
                    rowp[wi]      = f2bf((re * sn - im * cs) * oscale);
                    rowp[wi + 32] = f2bf((re * cs + im * sn) * oscale);
                }
            }
        }
    } else {
        #pragma unroll
        for (int mi = 0; mi < 2; ++mi) {
            #pragma unroll
            for (int r = 0; r < 4; ++r) {
                const int fo = fo0 + w*32 + 16*mi + quad*4 + r;
                const float bvv = bv[fo];
                unsigned short* rowp = Vtb + ((size_t)b * F_DIM + fo) * T_DIM + t0;
                #pragma unroll
                for (int nt = 0; nt < 4; ++nt)
                    rowp[16*nt + ln15] = f2bf(acc[mi][nt][r] + bvv);
            }
        }
    }
}

// ---------------- Kernel 2: S^T MFMA flash attention, 32q dual-sm waves ----
// 256 thr = 4 waves: half = w4>>1 owns k-range [half*1024,+1024); qg = w4&1
// owns q [q0+32qg, +32) as two 16-row B-frags. Each wave does BOTH softmax
// branches -> each K frag read feeds 2x, each V frag read feeds 4x MFMAs:
// per 64q-unit LDS drops 160->96 b128 vs R9. 2 blocks/CU (LDS 64KB, 512
// blocks) so barriers hide under the co-resident block. No prefetch regs
// (budget: O=128 + qa=32 + pf=32 + S=32 transient ~ 240 < 256 cap).
__global__ __launch_bounds__(256, 2)
void attn_kernel(const unsigned short* __restrict__ Qb,
                 const unsigned short* __restrict__ Kb,
                 const unsigned short* __restrict__ Vtb,
                 const float* __restrict__ x,
                 const float* __restrict__ s2g,
                 float* __restrict__ out)
{
    __shared__ unsigned short smem[2][16384];   // [half][K 16KB | V 16KB] = 64 KB

    const int tid  = threadIdx.x;
    const int w4   = tid >> 6;        // 0..3
    const int half = w4 >> 1;
    const int qg   = w4 & 1;
    const int lane = tid & 63;
    const int ln15 = lane & 15;
    const int quad = lane >> 4;
    const int t128 = tid & 127;

    const int q0 = blockIdx.x * 64;
    const int h  = blockIdx.y;
    const int b  = blockIdx.z;
    const int kbase = half << 10;   // 0 or 1024

    unsigned short* __restrict__ Ks = &smem[half][0];     // 64 x 128 (perm+swizzle)
    unsigned short* __restrict__ Vs = &smem[half][8192];  // 128 x 64 (swizzle)

    const unsigned short* __restrict__ Qg =
        Qb + ((size_t)b * T_DIM + q0 + qg * 32) * F_DIM + h * HF;
    const unsigned short* __restrict__ Kg =
        Kb + (size_t)b * T_DIM * F_DIM + h * HF;
    const unsigned short* __restrict__ Vg =
        Vtb + ((size_t)b * F_DIM + h * HF) * T_DIM;

    // Q B-frags (resident): qa[qh][c], B[k=feat 32c..][n=q=ln15]
    short8 qa[2][4];
    #pragma unroll
    for (int qh = 0; qh < 2; ++qh)
        #pragma unroll
        for (int c = 0; c < 4; ++c)
            qa[qh][c] = *(const short8*)(Qg + (size_t)(16*qh + ln15) * F_DIM + quad * 8 + 32 * c);

    floatx4 O[2][2][8];   // [sm][qh][ft] — O^T[feat=16ft+4quad+r][q]
    #pragma unroll
    for (int s = 0; s < 2; ++s)
        #pragma unroll
        for (int qh = 0; qh < 2; ++qh)
            #pragma unroll
            for (int ft = 0; ft < 8; ++ft)
                O[s][qh][ft] = (floatx4){0.f, 0.f, 0.f, 0.f};
    float l[2][2] = {{0.f, 0.f}, {0.f, 0.f}};

    for (int k0 = 0; k0 < 1024; k0 += 64) {
        __syncthreads();   // half's waves done reading previous tiles
        #pragma unroll
        for (int it = 0; it < 8; ++it) {
            const int idx = t128 + it * 128;
            const int r = idx >> 4, c = idx & 15;
            // row perm so P^T C-regs align with PV B-frag slots (verified R4-R9)
            const int rp = (r & 32) | ((r & 4) << 2) | ((r & 24) >> 1) | (r & 3);
            *(short8*)&Ks[rp * 128 + (c ^ (rp & 15)) * 8] =
                *(const short8*)(Kg + (size_t)(kbase + k0 + r) * F_DIM + c * 8);
        }
        #pragma unroll
        for (int it = 0; it < 8; ++it) {
            const int idx = t128 + it * 128;
            const int r = idx >> 3, c = idx & 7;
            *(short8*)&Vs[r * 64 + (c ^ (r & 7)) * 8] =
                *(const short8*)(Vg + (size_t)r * T_DIM + kbase + k0 + c * 8);
        }
        __syncthreads();   // tiles visible

        short8 pf[2][2][2];   // [sm][qh][pair]

        #pragma unroll
        for (int s = 0; s < 2; ++s) {
            floatx4 S[4][2];
            #pragma unroll
            for (int t = 0; t < 4; ++t) {
                const unsigned short* krow = &Ks[(16 * t + ln15) * 128];
                const short8 kA = *(const short8*)(krow + ((quad     + 8*s) ^ ln15) * 8);
                const short8 kB = *(const short8*)(krow + ((quad + 4 + 8*s) ^ ln15) * 8);
                #pragma unroll
                for (int qh = 0; qh < 2; ++qh) {
                    floatx4 z = (floatx4){0.f, 0.f, 0.f, 0.f};
                    floatx4 acc0 = __builtin_amdgcn_mfma_f32_16x16x32_bf16(kA, qa[qh][2*s    ], z, 0, 0, 0);
                    S[t][qh]     = __builtin_amdgcn_mfma_f32_16x16x32_bf16(kB, qa[qh][2*s + 1], acc0, 0, 0, 0);
                }
            }
            #pragma unroll
            for (int qh = 0; qh < 2; ++qh) {
                float e[16], smv = 0.f;
                #pragma unroll
                for (int t = 0; t < 4; ++t)
                    #pragma unroll
                    for (int r = 0; r < 4; ++r) {
                        const float v = __builtin_amdgcn_exp2f(S[t][qh][r]);
                        e[4*t + r] = v; smv += v;
                    }
                l[s][qh] += smv;
                pf[s][qh][0] = pack8(&e[0]);
                pf[s][qh][1] = pack8(&e[8]);
            }
        }

        // ---- PV: each V-frag read feeds 4 MFMAs ----
        #pragma unroll
        for (int p = 0; p < 2; ++p) {
            #pragma unroll
            for (int ft = 0; ft < 8; ++ft) {
                const short8 va = *(const short8*)
                    (&Vs[(16*ft + ln15) * 64 + (((4*p + quad) ^ (ln15 & 7))) * 8]);
                #pragma unroll
                for (int s = 0; s < 2; ++s)
                    #pragma unroll
                    for (int qh = 0; qh < 2; ++qh)
                        O[s][qh][ft] = __builtin_amdgcn_mfma_f32_16x16x32_bf16(
                            va, pf[s][qh][p], O[s][qh][ft], 0, 0, 0);
            }
        }
    }

    // ---- l: reduce across quads ----
    #pragma unroll
    for (int s = 0; s < 2; ++s)
        #pragma unroll
        for (int qh = 0; qh < 2; ++qh) {
            l[s][qh] += __shfl_xor(l[s][qh], 16);
            l[s][qh] += __shfl_xor(l[s][qh], 32);
        }

    // ---- cross-half combine ----
    float*   combf = (float*)&smem[0][0];
    floatx4* combv = (floatx4*)&smem[0][0];
    __syncthreads();                       // all tile reads done; smem reusable
    if (half == 1 && quad == 0) {          // l partials: 128 floats
        #pragma unroll
        for (int s = 0; s < 2; ++s)
            #pragma unroll
            for (int qh = 0; qh < 2; ++qh)
                combf[((qg*2 + s)*2 + qh)*16 + ln15] = l[s][qh];
    }
    __syncthreads();
    if (half == 0) {
        #pragma unroll
        for (int s = 0; s < 2; ++s)
            #pragma unroll
            for (int qh = 0; qh < 2; ++qh)
                l[s][qh] += combf[((qg*2 + s)*2 + qh)*16 + ln15];
    }
    __syncthreads();
    if (half == 1) {                       // O partials: 16384 floats (b128)
        #pragma unroll
        for (int s = 0; s < 2; ++s)
            #pragma unroll
            for (int qh = 0; qh < 2; ++qh)
                #pragma unroll
                for (int ft = 0; ft < 8; ++ft)
                    combv[(((qg*2 + s)*2 + qh)*8 + ft)*64 + lane] = O[s][qh][ft];
    }
    __syncthreads();
    if (half == 0) {
        const float s2h = s2g[h];
        const size_t obase = (size_t)b * F_DIM * T_DIM;
        const int f0 = h * HF;
        #pragma unroll
        for (int qh = 0; qh < 2; ++qh) {
            const float i1 = 1.f / l[0][qh];
            const float i2 = s2h / l[1][qh];
            const int t = q0 + qg * 32 + 16*qh + ln15;
            #pragma unroll
            for (int ft = 0; ft < 8; ++ft) {
                const floatx4 o1p = combv[(((qg*2 + 0)*2 + qh)*8 + ft)*64 + lane];
                const floatx4 o2p = combv[(((qg*2 + 1)*2 + qh)*8 + ft)*64 + lane];
                #pragma unroll
                for (int r = 0; r < 4; ++r) {
                    const int feat = 16*ft + 4*quad + r;
                    const size_t idx = obase + (size_t)(f0 + feat) * T_DIM + t;
                    out[idx] = x[idx] + (O[0][qh][ft][r] + o1p[r]) * i1
                                      - (O[1][qh][ft][r] + o2p[r]) * i2;
                }
            }
        }
    }
}

extern "C" void kernel_launch(void* const* d_in, const int* in_sizes, int n_in,
                              void* d_out, int out_size, void* d_ws, size_t ws_size,
                              hipStream_t stream)
{
    const float* x  = (const float*)d_in[0];
    const float* Wq = (const float*)d_in[1];
    const float* bq = (const float*)d_in[2];
    const float* Wk = (const float*)d_in[3];
    const float* bk = (const float*)d_in[4];
    const float* Wv = (const float*)d_in[5];
    const float* bv = (const float*)d_in[6];
    const float* s2 = (const float*)d_in[7];
    float* out = (float*)d_out;

    const size_t per = (size_t)B_DIM * T_DIM * F_DIM;
    const size_t wsz = (size_t)F_DIM * F_DIM;
    unsigned short* xt  = (unsigned short*)d_ws;
    unsigned short* Wqb = xt + per;
    unsigned short* Wkb = Wqb + wsz;
    unsigned short* Wvb = Wkb + wsz;
    unsigned short* Qb  = Wvb + wsz;
    unsigned short* Kb  = Qb + per;
    unsigned short* Vtb = Kb + per;

    hipLaunchKernelGGL(prep_kernel, dim3(32, 8, 5), dim3(256), 0, stream,
                       x, Wq, Wk, Wv, xt, Wqb, Wkb, Wvb);

    hipLaunchKernelGGL(proj_kernel, dim3(16, 8, 12), dim3(256), 0, stream,
                       xt, Wqb, Wkb, Wvb, bq, bk, bv, Qb, Kb, Vtb);

    hipLaunchKernelGGL(attn_kernel, dim3(32, 4, 4), dim3(256), 0, stream,
                       Qb, Kb, Vtb, x, s2, out);
}